// Round 1
// baseline (444.321 us; speedup 1.0000x reference)
//
#include <hip/hip_runtime.h>

// ConvAttention: B=8, C=64, H=W=256, 3x3, fp32.
// v2: occupancy fix. One block (256 thr = 4 waves) = ONE image row,
// 1 column per lane. Grid = (256, 8) = 2048 blocks = 8192 waves
// -> exactly 32 waves/CU (was 2048 waves total = 22% occupancy).
// Horizontal neighbors via direct [-1/+1] loads (L1-hit, overlapping
// lines) instead of __shfl -- no cross-wave boundary cases.
// XCD swizzle: XCD i gets image i, rows in dispatch order, so the
// +/-1-row vertical re-reads of k/v hit that XCD's private L2.

constexpr int B = 8, C = 64, H = 256, W = 256;

__global__ __launch_bounds__(256, 8) void conv_attn_kernel(
    const float* __restrict__ qg, const float* __restrict__ kg,
    const float* __restrict__ vg, float* __restrict__ og) {
  // Bijective XCD-aware remap of the linear block id (2048 % 8 == 0).
  const int lin = blockIdx.y * (int)gridDim.x + blockIdx.x;   // 0..2047
  const int swz = (lin & 7) * ((H * B) / 8) + (lin >> 3);
  const int y = swz & (H - 1);
  const int b = swz >> 8;          // swz / H
  const int x = threadIdx.x;       // 0..255: column

  const size_t cs   = (size_t)H * W;
  const size_t base = ((size_t)b * C) * cs + (size_t)y * W + x;
  const bool up = (y > 0), dn = (y < H - 1);
  const bool lok = (x > 0), rok = (x < W - 1);

  float s[9];
#pragma unroll
  for (int t = 0; t < 9; ++t) s[t] = 0.f;

  // ---------------- pass 1: scores ----------------
#pragma unroll 2
  for (int c = 0; c < C; ++c) {
    const size_t cb = base + (size_t)c * cs;
    const float qv = qg[cb];
    const float* kp = kg + cb;
    {  // row y-1
      float a = (up && lok) ? kp[-W - 1] : 0.f;
      float m = up ? kp[-W] : 0.f;
      float r = (up && rok) ? kp[-W + 1] : 0.f;
      s[0] = fmaf(qv, a, s[0]);
      s[1] = fmaf(qv, m, s[1]);
      s[2] = fmaf(qv, r, s[2]);
    }
    {  // row y
      float a = lok ? kp[-1] : 0.f;
      float m = kp[0];
      float r = rok ? kp[1] : 0.f;
      s[3] = fmaf(qv, a, s[3]);
      s[4] = fmaf(qv, m, s[4]);
      s[5] = fmaf(qv, r, s[5]);
    }
    {  // row y+1
      float a = (dn && lok) ? kp[W - 1] : 0.f;
      float m = dn ? kp[W] : 0.f;
      float r = (dn && rok) ? kp[W + 1] : 0.f;
      s[6] = fmaf(qv, a, s[6]);
      s[7] = fmaf(qv, m, s[7]);
      s[8] = fmaf(qv, r, s[8]);
    }
  }

  // ---------------- softmax over 9 taps ----------------
  {
    float m = s[0];
#pragma unroll
    for (int t = 1; t < 9; ++t) m = fmaxf(m, s[t]);
    float sum = 0.f;
#pragma unroll
    for (int t = 0; t < 9; ++t) { s[t] = __expf(s[t] - m); sum += s[t]; }
    float inv = 1.f / sum;
#pragma unroll
    for (int t = 0; t < 9; ++t) s[t] *= inv;
  }

  // ---------------- pass 2: weighted v sum ----------------
#pragma unroll 2
  for (int c = 0; c < C; ++c) {
    const size_t cb = base + (size_t)c * cs;
    const float* vp = vg + cb;
    float o = 0.f;
    {  // row y-1
      float a = (up && lok) ? vp[-W - 1] : 0.f;
      float m = up ? vp[-W] : 0.f;
      float r = (up && rok) ? vp[-W + 1] : 0.f;
      o = fmaf(s[0], a, o);
      o = fmaf(s[1], m, o);
      o = fmaf(s[2], r, o);
    }
    {  // row y
      float a = lok ? vp[-1] : 0.f;
      float m = vp[0];
      float r = rok ? vp[1] : 0.f;
      o = fmaf(s[3], a, o);
      o = fmaf(s[4], m, o);
      o = fmaf(s[5], r, o);
    }
    {  // row y+1
      float a = (dn && lok) ? vp[W - 1] : 0.f;
      float m = dn ? vp[W] : 0.f;
      float r = (dn && rok) ? vp[W + 1] : 0.f;
      o = fmaf(s[6], a, o);
      o = fmaf(s[7], m, o);
      o = fmaf(s[8], r, o);
    }
    og[cb] = o;
  }
}

extern "C" void kernel_launch(void* const* d_in, const int* in_sizes, int n_in,
                              void* d_out, int out_size, void* d_ws, size_t ws_size,
                              hipStream_t stream) {
  const float* q = (const float*)d_in[0];
  const float* k = (const float*)d_in[1];
  const float* v = (const float*)d_in[2];
  float* out = (float*)d_out;
  dim3 grid(H, B);
  conv_attn_kernel<<<grid, dim3(256), 0, stream>>>(q, k, v, out);
}